// Round 1
// baseline (544.400 us; speedup 1.0000x reference)
//
#include <hip/hip_runtime.h>
#include <hip/hip_bf16.h>

#define DEV static __device__ __forceinline__

typedef __attribute__((ext_vector_type(4))) float f32x4;
typedef __attribute__((ext_vector_type(8))) short s16x8;

constexpr int Bn = 4, Tn = 2048, Dn = 1024, Hn = 8, DH = 128;
constexpr float EPSF = 1e-5f;

DEV unsigned short f2bf(float f) {
    unsigned int u = __float_as_uint(f);
    u += 0x7FFF + ((u >> 16) & 1);   // round-to-nearest-even
    return (unsigned short)(u >> 16);
}

DEV f32x4 mfma16(s16x8 a, s16x8 b, f32x4 c) {
    return __builtin_amdgcn_mfma_f32_16x16x32_bf16(a, b, c, 0, 0, 0);
}

// ---------------- weight f32 -> bf16 conversion ----------------
__global__ void cvt_w_kernel(const float* __restrict__ qw, const float* __restrict__ kw,
                             const float* __restrict__ vw, const float* __restrict__ ow,
                             unsigned short* __restrict__ dst) {
    int idx = blockIdx.x * blockDim.x + threadIdx.x;
    const int total = 4 * Dn * Dn;
    for (; idx < total; idx += gridDim.x * blockDim.x) {
        int sel = idx >> 20;              // Dn*Dn == 2^20
        int off = idx & (Dn * Dn - 1);
        const float* src = sel == 0 ? qw : sel == 1 ? kw : sel == 2 ? vw : ow;
        dst[idx] = f2bf(src[off]);
    }
}

// ---------------- layernorm (full D), f32 in -> bf16 out ----------------
__global__ __launch_bounds__(256) void ln_kernel(const float* __restrict__ x,
                                                 const float* __restrict__ w,
                                                 const float* __restrict__ b,
                                                 unsigned short* __restrict__ xn) {
    int tok = blockIdx.x;          // 0..8191
    int tid = threadIdx.x;         // 0..255, 4 floats each
    const float* xp = x + (size_t)tok * Dn;
    float4 v = ((const float4*)xp)[tid];
    float s = v.x + v.y + v.z + v.w;
    float q = v.x * v.x + v.y * v.y + v.z * v.z + v.w * v.w;
    for (int off = 32; off; off >>= 1) {
        s += __shfl_xor(s, off);
        q += __shfl_xor(q, off);
    }
    __shared__ float red[8];
    __shared__ float stats[2];
    int wid = tid >> 6, lane = tid & 63;
    if (lane == 0) { red[wid] = s; red[4 + wid] = q; }
    __syncthreads();
    if (tid == 0) {
        float ts = red[0] + red[1] + red[2] + red[3];
        float tq = red[4] + red[5] + red[6] + red[7];
        float mu = ts / Dn;
        float var = tq / Dn - mu * mu;
        stats[0] = mu;
        stats[1] = rsqrtf(var + EPSF);
    }
    __syncthreads();
    float mu = stats[0], rs = stats[1];
    int c = tid * 4;
    ushort4 o;
    o.x = f2bf((v.x - mu) * rs * w[c + 0] + b[c + 0]);
    o.y = f2bf((v.y - mu) * rs * w[c + 1] + b[c + 1]);
    o.z = f2bf((v.z - mu) * rs * w[c + 2] + b[c + 2]);
    o.w = f2bf((v.w - mu) * rs * w[c + 3] + b[c + 3]);
    ((ushort4*)(xn + (size_t)tok * Dn))[tid] = o;
}

// ---------------- QKV projection: out[t][d] = sum_k xn[t][k]*W[d][k] + bias[d] ----------------
// grid: (8192/64, 1024/64, 3). 64x64 tile, 4 waves, 16x16x32 MFMA. K bound = m per expert chunk.
__global__ __launch_bounds__(256) void qkv_gemm(const unsigned short* __restrict__ xn,
                                                const unsigned short* __restrict__ wmat,
                                                const float* __restrict__ qb_,
                                                const float* __restrict__ kb_,
                                                const float* __restrict__ vb_,
                                                unsigned short* __restrict__ outq,
                                                unsigned short* __restrict__ outk,
                                                unsigned short* __restrict__ outv) {
    int rowbase = blockIdx.x * 64;
    int colbase = blockIdx.y * 64;
    int matid = blockIdx.z;
    const unsigned short* W = wmat + (size_t)matid * Dn * Dn;
    const float* bias = matid == 0 ? qb_ : matid == 1 ? kb_ : vb_;
    unsigned short* out = matid == 0 ? outq : matid == 1 ? outk : outv;
    float oscale = matid == 0 ? 0.03125f : 1.0f;   // fold attn scale 1/32 into Q
    int e = (rowbase & (Tn - 1)) >> 9;             // chunk within T
    int m = Dn >> e;

    __shared__ alignas(16) unsigned short At[64][32];
    __shared__ alignas(16) unsigned short Bt[64][32];

    int tid = threadIdx.x;
    int lr = tid >> 2;            // staging row 0..63
    int lc = (tid & 3) * 8;       // staging col 0,8,16,24
    int lane = tid & 63;
    int wv = tid >> 6;
    int wr = (wv >> 1) * 32, wc = (wv & 1) * 32;
    int fr = lane & 15, fg = lane >> 4;
    f32x4 acc[2][2] = {};

    for (int k = 0; k < m; k += 32) {
        __syncthreads();
        *(uint4*)&At[lr][lc] = *(const uint4*)&xn[(size_t)(rowbase + lr) * Dn + k + lc];
        *(uint4*)&Bt[lr][lc] = *(const uint4*)&W[(size_t)(colbase + lr) * Dn + k + lc];
        __syncthreads();
        s16x8 a0 = *(const s16x8*)&At[wr + fr][fg * 8];
        s16x8 a1 = *(const s16x8*)&At[wr + 16 + fr][fg * 8];
        s16x8 b0 = *(const s16x8*)&Bt[wc + fr][fg * 8];
        s16x8 b1 = *(const s16x8*)&Bt[wc + 16 + fr][fg * 8];
        acc[0][0] = mfma16(a0, b0, acc[0][0]);
        acc[0][1] = mfma16(a0, b1, acc[0][1]);
        acc[1][0] = mfma16(a1, b0, acc[1][0]);
        acc[1][1] = mfma16(a1, b1, acc[1][1]);
    }
    for (int i = 0; i < 2; i++)
        for (int j = 0; j < 2; j++) {
            int col = colbase + wc + j * 16 + fr;
            float bv = bias[col];
            for (int r = 0; r < 4; r++) {
                int row = rowbase + wr + i * 16 + fg * 4 + r;
                out[(size_t)row * Dn + col] = f2bf((acc[i][j][r] + bv) * oscale);
            }
        }
}

// ---------------- flash attention, bf16 MFMA ----------------
// grid: (T/64, H, B); block 256 = 4 waves, each wave owns 16 query rows.
__global__ __launch_bounds__(256) void attn_kernel(const unsigned short* __restrict__ Q,
                                                   const unsigned short* __restrict__ K,
                                                   const unsigned short* __restrict__ V,
                                                   unsigned short* __restrict__ AO) {
    int b = blockIdx.z, h = blockIdx.y;
    int qbase = blockIdx.x * 64;
    int tid = threadIdx.x;
    int wv = tid >> 6, lane = tid & 63;
    int fr = lane & 15, fg = lane >> 4;

    __shared__ alignas(16) unsigned short Kt[32][128];
    __shared__ alignas(16) unsigned short Vt[32][128];
    __shared__ alignas(16) unsigned short Pt[4][16][32];

    // Q fragments in registers (scale already folded in)
    const size_t qrow0 = ((size_t)b * Tn + qbase + wv * 16 + fr) * Dn + h * DH;
    s16x8 aq[4];
    for (int c = 0; c < 4; c++) aq[c] = *(const s16x8*)&Q[qrow0 + c * 32 + fg * 8];

    f32x4 acc[8] = {};
    float mrow[4], lrow[4];
    for (int r = 0; r < 4; r++) { mrow[r] = -1e30f; lrow[r] = 0.f; }

    int srow = tid >> 3;            // 0..31
    int scol = (tid & 7) * 16;      // 0..112

    for (int kb = 0; kb < Tn; kb += 32) {
        __syncthreads();  // protect Kt/Vt from previous iteration's readers
        const size_t kro = ((size_t)b * Tn + kb + srow) * Dn + h * DH + scol;
        *(uint4*)&Kt[srow][scol]     = *(const uint4*)&K[kro];
        *(uint4*)&Kt[srow][scol + 8] = *(const uint4*)&K[kro + 8];
        *(uint4*)&Vt[srow][scol]     = *(const uint4*)&V[kro];
        *(uint4*)&Vt[srow][scol + 8] = *(const uint4*)&V[kro + 8];
        __syncthreads();

        // S = Q K^T  (16 q x 32 k), two 16x16 tiles
        f32x4 s0 = {}, s1 = {};
        for (int c = 0; c < 4; c++) {
            s16x8 bk0 = *(const s16x8*)&Kt[fr][c * 32 + fg * 8];
            s16x8 bk1 = *(const s16x8*)&Kt[16 + fr][c * 32 + fg * 8];
            s0 = mfma16(aq[c], bk0, s0);
            s1 = mfma16(aq[c], bk1, s1);
        }

        // online softmax; lane holds rows fg*4+r, cols fr (tile0) and 16+fr (tile1)
        float f[4];
        for (int r = 0; r < 4; r++) {
            float mx = fmaxf(s0[r], s1[r]);
            for (int off = 1; off < 16; off <<= 1) mx = fmaxf(mx, __shfl_xor(mx, off));
            float mnew = fmaxf(mrow[r], mx);
            float p0 = __expf(s0[r] - mnew);
            float p1 = __expf(s1[r] - mnew);
            float rs = p0 + p1;
            for (int off = 1; off < 16; off <<= 1) rs += __shfl_xor(rs, off);
            f[r] = __expf(mrow[r] - mnew);
            lrow[r] = lrow[r] * f[r] + rs;
            mrow[r] = mnew;
            Pt[wv][fg * 4 + r][fr]      = f2bf(p0);
            Pt[wv][fg * 4 + r][16 + fr] = f2bf(p1);
        }
        for (int n = 0; n < 8; n++)
            for (int r = 0; r < 4; r++) acc[n][r] *= f[r];
        __syncthreads();  // make P visible (cross-lane through LDS)

        // O += P V : A-frag from Pt (contiguous), B-frag gathered from Vt
        s16x8 pa = *(const s16x8*)&Pt[wv][fr][fg * 8];
        for (int n = 0; n < 8; n++) {
            s16x8 bvv;
            for (int j = 0; j < 8; j++) bvv[j] = (short)Vt[fg * 8 + j][n * 16 + fr];
            acc[n] = mfma16(pa, bvv, acc[n]);
        }
    }

    size_t orow0 = ((size_t)b * Tn + qbase + wv * 16) * Dn + h * DH;
    for (int n = 0; n < 8; n++)
        for (int r = 0; r < 4; r++) {
            float v = acc[n][r] / lrow[r];
            AO[orow0 + (size_t)(fg * 4 + r) * Dn + n * 16 + fr] = f2bf(v);
        }
}

// ---------------- O projection + pad + residual ----------------
// out[t][o] = sum_{k<m} ao[t][k]*o_w[o][k] + o_b[o] + x[t][o]   (o < m)
// out[t][o] = x[t][o]                                           (o >= m)
__global__ __launch_bounds__(256) void oproj_gemm(const unsigned short* __restrict__ A,
                                                  const unsigned short* __restrict__ W,
                                                  const float* __restrict__ bias,
                                                  const float* __restrict__ x,
                                                  float* __restrict__ out) {
    int rowbase = blockIdx.x * 64;
    int colbase = blockIdx.y * 64;
    int e = (rowbase & (Tn - 1)) >> 9;
    int m = Dn >> e;
    int tid = threadIdx.x;

    if (colbase >= m) {   // pad region: pure residual copy
        for (int i = 0; i < 16; i++) {
            int idx = i * 256 + tid;
            int r = idx >> 6, c = idx & 63;
            size_t g = (size_t)(rowbase + r) * Dn + colbase + c;
            out[g] = x[g];
        }
        return;
    }

    __shared__ alignas(16) unsigned short At[64][32];
    __shared__ alignas(16) unsigned short Bt[64][32];
    int lr = tid >> 2, lc = (tid & 3) * 8;
    int lane = tid & 63, wv = tid >> 6;
    int wr = (wv >> 1) * 32, wc = (wv & 1) * 32;
    int fr = lane & 15, fg = lane >> 4;
    f32x4 acc[2][2] = {};

    for (int k = 0; k < m; k += 32) {
        __syncthreads();
        *(uint4*)&At[lr][lc] = *(const uint4*)&A[(size_t)(rowbase + lr) * Dn + k + lc];
        *(uint4*)&Bt[lr][lc] = *(const uint4*)&W[(size_t)(colbase + lr) * Dn + k + lc];
        __syncthreads();
        s16x8 a0 = *(const s16x8*)&At[wr + fr][fg * 8];
        s16x8 a1 = *(const s16x8*)&At[wr + 16 + fr][fg * 8];
        s16x8 b0 = *(const s16x8*)&Bt[wc + fr][fg * 8];
        s16x8 b1 = *(const s16x8*)&Bt[wc + 16 + fr][fg * 8];
        acc[0][0] = mfma16(a0, b0, acc[0][0]);
        acc[0][1] = mfma16(a0, b1, acc[0][1]);
        acc[1][0] = mfma16(a1, b0, acc[1][0]);
        acc[1][1] = mfma16(a1, b1, acc[1][1]);
    }
    for (int i = 0; i < 2; i++)
        for (int j = 0; j < 2; j++) {
            int col = colbase + wc + j * 16 + fr;
            float bv = bias[col];
            for (int r = 0; r < 4; r++) {
                int row = rowbase + wr + i * 16 + fg * 4 + r;
                size_t g = (size_t)row * Dn + col;
                out[g] = acc[i][j][r] + bv + x[g];
            }
        }
}

extern "C" void kernel_launch(void* const* d_in, const int* in_sizes, int n_in,
                              void* d_out, int out_size, void* d_ws, size_t ws_size,
                              hipStream_t stream) {
    const float* x   = (const float*)d_in[0];
    // d_in[1] router_prob: only shape is used by reference -> unused here
    const float* nw  = (const float*)d_in[2];
    const float* nb  = (const float*)d_in[3];
    const float* qw  = (const float*)d_in[4];
    const float* qb_ = (const float*)d_in[5];
    const float* kw  = (const float*)d_in[6];
    const float* kb_ = (const float*)d_in[7];
    const float* vw  = (const float*)d_in[8];
    const float* vb_ = (const float*)d_in[9];
    const float* ow  = (const float*)d_in[10];
    const float* ob_ = (const float*)d_in[11];
    float* out = (float*)d_out;

    unsigned short* ws = (unsigned short*)d_ws;
    const size_t NTOK = (size_t)Bn * Tn;        // 8192
    unsigned short* xn = ws;                    // layernorm output, bf16
    unsigned short* qd = xn + NTOK * Dn;
    unsigned short* kd = qd + NTOK * Dn;
    unsigned short* vd = kd + NTOK * Dn;
    unsigned short* ao = vd + NTOK * Dn;        // attention output, bf16
    unsigned short* wb = ao + NTOK * Dn;        // [wq|wk|wv|wo] bf16

    hipLaunchKernelGGL(cvt_w_kernel, dim3(4096), dim3(256), 0, stream, qw, kw, vw, ow, wb);
    hipLaunchKernelGGL(ln_kernel, dim3(NTOK), dim3(256), 0, stream, x, nw, nb, xn);
    hipLaunchKernelGGL(qkv_gemm, dim3(128, 16, 3), dim3(256), 0, stream,
                       xn, wb, qb_, kb_, vb_, qd, kd, vd);
    hipLaunchKernelGGL(attn_kernel, dim3(Tn / 64, Hn, Bn), dim3(256), 0, stream, qd, kd, vd, ao);
    hipLaunchKernelGGL(oproj_gemm, dim3(128, 16), dim3(256), 0, stream,
                       ao, wb + (size_t)3 * Dn * Dn, ob_, x, out);
}

// Round 2
// 337.361 us; speedup vs baseline: 1.6137x; 1.6137x over previous
//
#include <hip/hip_runtime.h>
#include <hip/hip_bf16.h>

#define DEV static __device__ __forceinline__

typedef __attribute__((ext_vector_type(4))) float f32x4;
typedef __attribute__((ext_vector_type(8))) short s16x8;

constexpr int Bn = 4, Tn = 2048, Dn = 1024, Hn = 8, DH = 128;
constexpr float EPSF = 1e-5f;

DEV unsigned short f2bf(float f) {
    unsigned int u = __float_as_uint(f);
    u += 0x7FFF + ((u >> 16) & 1);   // round-to-nearest-even
    return (unsigned short)(u >> 16);
}

DEV f32x4 mfma16(s16x8 a, s16x8 b, f32x4 c) {
    return __builtin_amdgcn_mfma_f32_16x16x32_bf16(a, b, c, 0, 0, 0);
}

// ---------------- weight f32 -> bf16 conversion ----------------
__global__ void cvt_w_kernel(const float* __restrict__ qw, const float* __restrict__ kw,
                             const float* __restrict__ vw, const float* __restrict__ ow,
                             unsigned short* __restrict__ dst) {
    int idx = blockIdx.x * blockDim.x + threadIdx.x;
    const int total = 4 * Dn * Dn;
    for (; idx < total; idx += gridDim.x * blockDim.x) {
        int sel = idx >> 20;              // Dn*Dn == 2^20
        int off = idx & (Dn * Dn - 1);
        const float* src = sel == 0 ? qw : sel == 1 ? kw : sel == 2 ? vw : ow;
        dst[idx] = f2bf(src[off]);
    }
}

// ---------------- layernorm (full D), f32 in -> bf16 out ----------------
__global__ __launch_bounds__(256) void ln_kernel(const float* __restrict__ x,
                                                 const float* __restrict__ w,
                                                 const float* __restrict__ b,
                                                 unsigned short* __restrict__ xn) {
    int tok = blockIdx.x;          // 0..8191
    int tid = threadIdx.x;         // 0..255, 4 floats each
    const float* xp = x + (size_t)tok * Dn;
    float4 v = ((const float4*)xp)[tid];
    float s = v.x + v.y + v.z + v.w;
    float q = v.x * v.x + v.y * v.y + v.z * v.z + v.w * v.w;
    for (int off = 32; off; off >>= 1) {
        s += __shfl_xor(s, off);
        q += __shfl_xor(q, off);
    }
    __shared__ float red[8];
    __shared__ float stats[2];
    int wid = tid >> 6, lane = tid & 63;
    if (lane == 0) { red[wid] = s; red[4 + wid] = q; }
    __syncthreads();
    if (tid == 0) {
        float ts = red[0] + red[1] + red[2] + red[3];
        float tq = red[4] + red[5] + red[6] + red[7];
        float mu = ts / Dn;
        float var = tq / Dn - mu * mu;
        stats[0] = mu;
        stats[1] = rsqrtf(var + EPSF);
    }
    __syncthreads();
    float mu = stats[0], rs = stats[1];
    int c = tid * 4;
    ushort4 o;
    o.x = f2bf((v.x - mu) * rs * w[c + 0] + b[c + 0]);
    o.y = f2bf((v.y - mu) * rs * w[c + 1] + b[c + 1]);
    o.z = f2bf((v.z - mu) * rs * w[c + 2] + b[c + 2]);
    o.w = f2bf((v.w - mu) * rs * w[c + 3] + b[c + 3]);
    ((ushort4*)(xn + (size_t)tok * Dn))[tid] = o;
}

// ---------------- QKV projection ----------------
// out[t][d] = sum_k xn[t][k]*W[d][k] + bias[d].  V is written TRANSPOSED to
// vt[b][h][d][t] so attention's PV B-fragments are contiguous vector reads.
__global__ __launch_bounds__(256) void qkv_gemm(const unsigned short* __restrict__ xn,
                                                const unsigned short* __restrict__ wmat,
                                                const float* __restrict__ qb_,
                                                const float* __restrict__ kb_,
                                                const float* __restrict__ vb_,
                                                unsigned short* __restrict__ outq,
                                                unsigned short* __restrict__ outk,
                                                unsigned short* __restrict__ vt) {
    int rowbase = blockIdx.x * 64;
    int colbase = blockIdx.y * 64;
    int matid = blockIdx.z;
    const unsigned short* W = wmat + (size_t)matid * Dn * Dn;
    const float* bias = matid == 0 ? qb_ : matid == 1 ? kb_ : vb_;
    float oscale = matid == 0 ? 0.03125f : 1.0f;   // fold attn scale 1/32 into Q
    int e = (rowbase & (Tn - 1)) >> 9;             // chunk within T
    int m = Dn >> e;

    __shared__ alignas(16) unsigned short At[64][32];
    __shared__ alignas(16) unsigned short Bt[64][32];

    int tid = threadIdx.x;
    int lr = tid >> 2;            // staging row 0..63
    int lc = (tid & 3) * 8;       // staging col 0,8,16,24
    int lane = tid & 63;
    int wv = tid >> 6;
    int wr = (wv >> 1) * 32, wc = (wv & 1) * 32;
    int fr = lane & 15, fg = lane >> 4;
    f32x4 acc[2][2] = {};

    for (int k = 0; k < m; k += 32) {
        __syncthreads();
        *(uint4*)&At[lr][lc] = *(const uint4*)&xn[(size_t)(rowbase + lr) * Dn + k + lc];
        *(uint4*)&Bt[lr][lc] = *(const uint4*)&W[(size_t)(colbase + lr) * Dn + k + lc];
        __syncthreads();
        s16x8 a0 = *(const s16x8*)&At[wr + fr][fg * 8];
        s16x8 a1 = *(const s16x8*)&At[wr + 16 + fr][fg * 8];
        s16x8 b0 = *(const s16x8*)&Bt[wc + fr][fg * 8];
        s16x8 b1 = *(const s16x8*)&Bt[wc + 16 + fr][fg * 8];
        acc[0][0] = mfma16(a0, b0, acc[0][0]);
        acc[0][1] = mfma16(a0, b1, acc[0][1]);
        acc[1][0] = mfma16(a1, b0, acc[1][0]);
        acc[1][1] = mfma16(a1, b1, acc[1][1]);
    }
    if (matid == 2) {
        // V: write transposed vt[((b*H + h)*DH + dh)*Tn + t]
        for (int i = 0; i < 2; i++)
            for (int j = 0; j < 2; j++) {
                int col = colbase + wc + j * 16 + fr;
                float bv = bias[col];
                int row0 = rowbase + wr + i * 16 + fg * 4;   // 4 consecutive t
                int bb = row0 >> 11, tl = row0 & (Tn - 1);
                size_t base = (((size_t)bb * Hn + (col >> 7)) * DH + (col & (DH - 1))) * Tn + tl;
                ushort4 o;
                o.x = f2bf(acc[i][j][0] + bv);
                o.y = f2bf(acc[i][j][1] + bv);
                o.z = f2bf(acc[i][j][2] + bv);
                o.w = f2bf(acc[i][j][3] + bv);
                *(ushort4*)&vt[base] = o;
            }
    } else {
        unsigned short* out = matid == 0 ? outq : outk;
        for (int i = 0; i < 2; i++)
            for (int j = 0; j < 2; j++) {
                int col = colbase + wc + j * 16 + fr;
                float bv = bias[col];
                for (int r = 0; r < 4; r++) {
                    int row = rowbase + wr + i * 16 + fg * 4 + r;
                    out[(size_t)row * Dn + col] = f2bf((acc[i][j][r] + bv) * oscale);
                }
            }
    }
}

// ---------------- flash attention, bf16 MFMA ----------------
// grid: (T/64, H, B); block 256 = 4 waves, each wave owns 16 query rows.
// KVBLK=64. V comes pre-transposed (vt[b][h][d][t]). All LDS tiles padded to
// non-pow2 strides so ds_read_b128 hits 8 distinct 16B slots (full LDS BW).
__global__ __launch_bounds__(256) void attn_kernel(const unsigned short* __restrict__ Q,
                                                   const unsigned short* __restrict__ K,
                                                   const unsigned short* __restrict__ VT,
                                                   unsigned short* __restrict__ AO) {
    int b = blockIdx.z, h = blockIdx.y;
    int qbase = blockIdx.x * 64;
    int tid = threadIdx.x;
    int wv = tid >> 6, lane = tid & 63;
    int fr = lane & 15, fg = lane >> 4;

    __shared__ alignas(16) unsigned short Kt[64][136];     // [key][d], pad->stride 272B
    __shared__ alignas(16) unsigned short VTt[128][72];    // [d][key], pad->stride 144B
    __shared__ alignas(16) unsigned short Pt[4][16][72];   // [wave][q][key]

    // Q fragments in registers (scale already folded in)
    const size_t qrow0 = ((size_t)b * Tn + qbase + wv * 16 + fr) * Dn + h * DH;
    s16x8 aq[4];
    for (int c = 0; c < 4; c++) aq[c] = *(const s16x8*)&Q[qrow0 + c * 32 + fg * 8];

    f32x4 acc[8] = {};
    float mrow[4], lrow[4];
    for (int r = 0; r < 4; r++) { mrow[r] = -1e30f; lrow[r] = 0.f; }

    int krow = tid >> 2, kcol = (tid & 3) * 8;     // K staging: 4 x uint4 / thread
    int vrow = tid >> 1, vcol = (tid & 1) * 32;    // VT staging: 4 x uint4 / thread

    const unsigned short* kgb = K + ((size_t)b * Tn + krow) * Dn + h * DH + kcol;
    const unsigned short* vgb = VT + (((size_t)b * Hn + h) * DH + vrow) * Tn + vcol;

    for (int kb = 0; kb < Tn; kb += 64) {
        __syncthreads();   // previous iteration's readers done
        const unsigned short* kg = kgb + (size_t)kb * Dn;
        #pragma unroll
        for (int p = 0; p < 4; p++)
            *(uint4*)&Kt[krow][kcol + p * 32] = *(const uint4*)&kg[p * 32];
        const unsigned short* vg = vgb + kb;
        #pragma unroll
        for (int p = 0; p < 4; p++)
            *(uint4*)&VTt[vrow][vcol + p * 8] = *(const uint4*)&vg[p * 8];
        __syncthreads();

        // S = Q K^T : four 16x16 key tiles
        f32x4 s[4] = {};
        #pragma unroll
        for (int c = 0; c < 4; c++) {
            #pragma unroll
            for (int kt = 0; kt < 4; kt++) {
                s16x8 bk = *(const s16x8*)&Kt[kt * 16 + fr][c * 32 + fg * 8];
                s[kt] = mfma16(aq[c], bk, s[kt]);
            }
        }

        // online softmax; lane holds query row fg*4+r, key col fr within each tile
        float f[4];
        #pragma unroll
        for (int r = 0; r < 4; r++) {
            float mx = fmaxf(fmaxf(s[0][r], s[1][r]), fmaxf(s[2][r], s[3][r]));
            #pragma unroll
            for (int off = 1; off < 16; off <<= 1) mx = fmaxf(mx, __shfl_xor(mx, off));
            float mnew = fmaxf(mrow[r], mx);
            float p0 = __expf(s[0][r] - mnew);
            float p1 = __expf(s[1][r] - mnew);
            float p2 = __expf(s[2][r] - mnew);
            float p3 = __expf(s[3][r] - mnew);
            float rs = p0 + p1 + p2 + p3;
            #pragma unroll
            for (int off = 1; off < 16; off <<= 1) rs += __shfl_xor(rs, off);
            f[r] = __expf(mrow[r] - mnew);
            lrow[r] = lrow[r] * f[r] + rs;
            mrow[r] = mnew;
            int qr = fg * 4 + r;
            Pt[wv][qr][fr]      = f2bf(p0);
            Pt[wv][qr][16 + fr] = f2bf(p1);
            Pt[wv][qr][32 + fr] = f2bf(p2);
            Pt[wv][qr][48 + fr] = f2bf(p3);
        }
        #pragma unroll
        for (int n = 0; n < 8; n++)
            #pragma unroll
            for (int r = 0; r < 4; r++) acc[n][r] *= f[r];
        __syncthreads();   // Pt visible (cross-lane through LDS)

        // O += P V : A-frag from Pt, B-frag contiguous from VTt
        #pragma unroll
        for (int ks = 0; ks < 2; ks++) {
            s16x8 pa = *(const s16x8*)&Pt[wv][fr][ks * 32 + fg * 8];
            #pragma unroll
            for (int n = 0; n < 8; n++) {
                s16x8 bv = *(const s16x8*)&VTt[n * 16 + fr][ks * 32 + fg * 8];
                acc[n] = mfma16(pa, bv, acc[n]);
            }
        }
    }

    size_t orow0 = ((size_t)b * Tn + qbase + wv * 16) * Dn + h * DH;
    for (int n = 0; n < 8; n++)
        for (int r = 0; r < 4; r++) {
            float v = acc[n][r] / lrow[r];
            AO[orow0 + (size_t)(fg * 4 + r) * Dn + n * 16 + fr] = f2bf(v);
        }
}

// ---------------- O projection + pad + residual ----------------
__global__ __launch_bounds__(256) void oproj_gemm(const unsigned short* __restrict__ A,
                                                  const unsigned short* __restrict__ W,
                                                  const float* __restrict__ bias,
                                                  const float* __restrict__ x,
                                                  float* __restrict__ out) {
    int rowbase = blockIdx.x * 64;
    int colbase = blockIdx.y * 64;
    int e = (rowbase & (Tn - 1)) >> 9;
    int m = Dn >> e;
    int tid = threadIdx.x;

    if (colbase >= m) {   // pad region: pure residual copy
        for (int i = 0; i < 16; i++) {
            int idx = i * 256 + tid;
            int r = idx >> 6, c = idx & 63;
            size_t g = (size_t)(rowbase + r) * Dn + colbase + c;
            out[g] = x[g];
        }
        return;
    }

    __shared__ alignas(16) unsigned short At[64][32];
    __shared__ alignas(16) unsigned short Bt[64][32];
    int lr = tid >> 2, lc = (tid & 3) * 8;
    int lane = tid & 63, wv = tid >> 6;
    int wr = (wv >> 1) * 32, wc = (wv & 1) * 32;
    int fr = lane & 15, fg = lane >> 4;
    f32x4 acc[2][2] = {};

    for (int k = 0; k < m; k += 32) {
        __syncthreads();
        *(uint4*)&At[lr][lc] = *(const uint4*)&A[(size_t)(rowbase + lr) * Dn + k + lc];
        *(uint4*)&Bt[lr][lc] = *(const uint4*)&W[(size_t)(colbase + lr) * Dn + k + lc];
        __syncthreads();
        s16x8 a0 = *(const s16x8*)&At[wr + fr][fg * 8];
        s16x8 a1 = *(const s16x8*)&At[wr + 16 + fr][fg * 8];
        s16x8 b0 = *(const s16x8*)&Bt[wc + fr][fg * 8];
        s16x8 b1 = *(const s16x8*)&Bt[wc + 16 + fr][fg * 8];
        acc[0][0] = mfma16(a0, b0, acc[0][0]);
        acc[0][1] = mfma16(a0, b1, acc[0][1]);
        acc[1][0] = mfma16(a1, b0, acc[1][0]);
        acc[1][1] = mfma16(a1, b1, acc[1][1]);
    }
    for (int i = 0; i < 2; i++)
        for (int j = 0; j < 2; j++) {
            int col = colbase + wc + j * 16 + fr;
            float bv = bias[col];
            for (int r = 0; r < 4; r++) {
                int row = rowbase + wr + i * 16 + fg * 4 + r;
                size_t g = (size_t)row * Dn + col;
                out[g] = acc[i][j][r] + bv + x[g];
            }
        }
}

extern "C" void kernel_launch(void* const* d_in, const int* in_sizes, int n_in,
                              void* d_out, int out_size, void* d_ws, size_t ws_size,
                              hipStream_t stream) {
    const float* x   = (const float*)d_in[0];
    const float* nw  = (const float*)d_in[2];
    const float* nb  = (const float*)d_in[3];
    const float* qw  = (const float*)d_in[4];
    const float* qb_ = (const float*)d_in[5];
    const float* kw  = (const float*)d_in[6];
    const float* kb_ = (const float*)d_in[7];
    const float* vw  = (const float*)d_in[8];
    const float* vb_ = (const float*)d_in[9];
    const float* ow  = (const float*)d_in[10];
    const float* ob_ = (const float*)d_in[11];
    float* out = (float*)d_out;

    unsigned short* ws = (unsigned short*)d_ws;
    const size_t NTOK = (size_t)Bn * Tn;        // 8192
    unsigned short* xn = ws;                    // layernorm output, bf16
    unsigned short* qd = xn + NTOK * Dn;
    unsigned short* kd = qd + NTOK * Dn;
    unsigned short* vt = kd + NTOK * Dn;        // V transposed [B][H][DH][T]
    unsigned short* ao = vt + NTOK * Dn;        // attention output, bf16
    unsigned short* wb = ao + NTOK * Dn;        // [wq|wk|wv|wo] bf16

    hipLaunchKernelGGL(cvt_w_kernel, dim3(4096), dim3(256), 0, stream, qw, kw, vw, ow, wb);
    hipLaunchKernelGGL(ln_kernel, dim3(NTOK), dim3(256), 0, stream, x, nw, nb, xn);
    hipLaunchKernelGGL(qkv_gemm, dim3(128, 16, 3), dim3(256), 0, stream,
                       xn, wb, qb_, kb_, vb_, qd, kd, vt);
    hipLaunchKernelGGL(attn_kernel, dim3(Tn / 64, Hn, Bn), dim3(256), 0, stream, qd, kd, vt, ao);
    hipLaunchKernelGGL(oproj_gemm, dim3(128, 16), dim3(256), 0, stream,
                       ao, wb + (size_t)3 * Dn * Dn, ob_, x, out);
}

// Round 3
// 289.036 us; speedup vs baseline: 1.8835x; 1.1672x over previous
//
#include <hip/hip_runtime.h>
#include <hip/hip_bf16.h>

#define DEV static __device__ __forceinline__

typedef __attribute__((ext_vector_type(4))) float f32x4;
typedef __attribute__((ext_vector_type(8))) short s16x8;

constexpr int Bn = 4, Tn = 2048, Dn = 1024, Hn = 8, DH = 128;
constexpr float EPSF = 1e-5f;
// attn scale (1/32) * log2(e): softmax done in exp2 domain
constexpr float QSCALE = 0.0450842200277801f;

DEV unsigned short f2bf(float f) {
    unsigned int u = __float_as_uint(f);
    u += 0x7FFF + ((u >> 16) & 1);   // round-to-nearest-even
    return (unsigned short)(u >> 16);
}

DEV f32x4 mfma16(s16x8 a, s16x8 b, f32x4 c) {
    return __builtin_amdgcn_mfma_f32_16x16x32_bf16(a, b, c, 0, 0, 0);
}

DEV float ex2(float x) {            // v_exp_f32 IS exp2
    float r;
    asm("v_exp_f32 %0, %1" : "=v"(r) : "v"(x));
    return r;
}

DEV unsigned int cvtpk(float lo, float hi) {   // bf16(lo) | bf16(hi)<<16, RNE
    unsigned int r;
    asm("v_cvt_pk_bf16_f32 %0, %1, %2" : "=v"(r) : "v"(lo), "v"(hi));
    return r;
}

// ---------------- weight f32 -> bf16 conversion ----------------
__global__ void cvt_w_kernel(const float* __restrict__ qw, const float* __restrict__ kw,
                             const float* __restrict__ vw, const float* __restrict__ ow,
                             unsigned short* __restrict__ dst) {
    int idx = blockIdx.x * blockDim.x + threadIdx.x;
    const int total = 4 * Dn * Dn;
    for (; idx < total; idx += gridDim.x * blockDim.x) {
        int sel = idx >> 20;              // Dn*Dn == 2^20
        int off = idx & (Dn * Dn - 1);
        const float* src = sel == 0 ? qw : sel == 1 ? kw : sel == 2 ? vw : ow;
        dst[idx] = f2bf(src[off]);
    }
}

// ---------------- layernorm (full D), f32 in -> bf16 out ----------------
__global__ __launch_bounds__(256) void ln_kernel(const float* __restrict__ x,
                                                 const float* __restrict__ w,
                                                 const float* __restrict__ b,
                                                 unsigned short* __restrict__ xn) {
    int tok = blockIdx.x;          // 0..8191
    int tid = threadIdx.x;         // 0..255, 4 floats each
    const float* xp = x + (size_t)tok * Dn;
    float4 v = ((const float4*)xp)[tid];
    float s = v.x + v.y + v.z + v.w;
    float q = v.x * v.x + v.y * v.y + v.z * v.z + v.w * v.w;
    for (int off = 32; off; off >>= 1) {
        s += __shfl_xor(s, off);
        q += __shfl_xor(q, off);
    }
    __shared__ float red[8];
    __shared__ float stats[2];
    int wid = tid >> 6, lane = tid & 63;
    if (lane == 0) { red[wid] = s; red[4 + wid] = q; }
    __syncthreads();
    if (tid == 0) {
        float ts = red[0] + red[1] + red[2] + red[3];
        float tq = red[4] + red[5] + red[6] + red[7];
        float mu = ts / Dn;
        float var = tq / Dn - mu * mu;
        stats[0] = mu;
        stats[1] = rsqrtf(var + EPSF);
    }
    __syncthreads();
    float mu = stats[0], rs = stats[1];
    int c = tid * 4;
    ushort4 o;
    o.x = f2bf((v.x - mu) * rs * w[c + 0] + b[c + 0]);
    o.y = f2bf((v.y - mu) * rs * w[c + 1] + b[c + 1]);
    o.z = f2bf((v.z - mu) * rs * w[c + 2] + b[c + 2]);
    o.w = f2bf((v.w - mu) * rs * w[c + 3] + b[c + 3]);
    ((ushort4*)(xn + (size_t)tok * Dn))[tid] = o;
}

// ---------------- QKV projection ----------------
// out[t][d] = sum_k xn[t][k]*W[d][k] + bias[d].  V is written TRANSPOSED to
// vt[b][h][d][t] so attention's PV B-fragments are contiguous vector reads.
__global__ __launch_bounds__(256) void qkv_gemm(const unsigned short* __restrict__ xn,
                                                const unsigned short* __restrict__ wmat,
                                                const float* __restrict__ qb_,
                                                const float* __restrict__ kb_,
                                                const float* __restrict__ vb_,
                                                unsigned short* __restrict__ outq,
                                                unsigned short* __restrict__ outk,
                                                unsigned short* __restrict__ vt) {
    int rowbase = blockIdx.x * 64;
    int colbase = blockIdx.y * 64;
    int matid = blockIdx.z;
    const unsigned short* W = wmat + (size_t)matid * Dn * Dn;
    const float* bias = matid == 0 ? qb_ : matid == 1 ? kb_ : vb_;
    float oscale = matid == 0 ? QSCALE : 1.0f;     // fold attn scale * log2e into Q
    int e = (rowbase & (Tn - 1)) >> 9;             // chunk within T
    int m = Dn >> e;

    __shared__ alignas(16) unsigned short At[64][32];
    __shared__ alignas(16) unsigned short Bt[64][32];

    int tid = threadIdx.x;
    int lr = tid >> 2;            // staging row 0..63
    int lc = (tid & 3) * 8;       // staging col 0,8,16,24
    int lane = tid & 63;
    int wv = tid >> 6;
    int wr = (wv >> 1) * 32, wc = (wv & 1) * 32;
    int fr = lane & 15, fg = lane >> 4;
    f32x4 acc[2][2] = {};

    for (int k = 0; k < m; k += 32) {
        __syncthreads();
        *(uint4*)&At[lr][lc] = *(const uint4*)&xn[(size_t)(rowbase + lr) * Dn + k + lc];
        *(uint4*)&Bt[lr][lc] = *(const uint4*)&W[(size_t)(colbase + lr) * Dn + k + lc];
        __syncthreads();
        s16x8 a0 = *(const s16x8*)&At[wr + fr][fg * 8];
        s16x8 a1 = *(const s16x8*)&At[wr + 16 + fr][fg * 8];
        s16x8 b0 = *(const s16x8*)&Bt[wc + fr][fg * 8];
        s16x8 b1 = *(const s16x8*)&Bt[wc + 16 + fr][fg * 8];
        acc[0][0] = mfma16(a0, b0, acc[0][0]);
        acc[0][1] = mfma16(a0, b1, acc[0][1]);
        acc[1][0] = mfma16(a1, b0, acc[1][0]);
        acc[1][1] = mfma16(a1, b1, acc[1][1]);
    }
    if (matid == 2) {
        // V: write transposed vt[((b*H + h)*DH + dh)*Tn + t]
        for (int i = 0; i < 2; i++)
            for (int j = 0; j < 2; j++) {
                int col = colbase + wc + j * 16 + fr;
                float bv = bias[col];
                int row0 = rowbase + wr + i * 16 + fg * 4;   // 4 consecutive t
                int bb = row0 >> 11, tl = row0 & (Tn - 1);
                size_t base = (((size_t)bb * Hn + (col >> 7)) * DH + (col & (DH - 1))) * Tn + tl;
                ushort4 o;
                o.x = f2bf(acc[i][j][0] + bv);
                o.y = f2bf(acc[i][j][1] + bv);
                o.z = f2bf(acc[i][j][2] + bv);
                o.w = f2bf(acc[i][j][3] + bv);
                *(ushort4*)&vt[base] = o;
            }
    } else {
        unsigned short* out = matid == 0 ? outq : outk;
        for (int i = 0; i < 2; i++)
            for (int j = 0; j < 2; j++) {
                int col = colbase + wc + j * 16 + fr;
                float bv = bias[col];
                for (int r = 0; r < 4; r++) {
                    int row = rowbase + wr + i * 16 + fg * 4 + r;
                    out[(size_t)row * Dn + col] = f2bf((acc[i][j][r] + bv) * oscale);
                }
            }
    }
}

// ---------------- flash attention, swapped-QK in-register softmax ----------------
// grid: (T/64, H, B); block 256 = 4 waves, each wave owns 16 query rows, KVBLK=64.
// S^T = mfma(K_frag, Q_frag): lane holds q=lane&15, keys kt*16+(lane>>4)*4+r in regs
// -> softmax is in-register (2 shfl_xor for cross-fg reduce), P packed via
// v_cvt_pk_bf16_f32 into wave-private LDS (no barrier), PV reads contiguous.
__global__ __launch_bounds__(256) void attn_kernel(const unsigned short* __restrict__ Q,
                                                   const unsigned short* __restrict__ K,
                                                   const unsigned short* __restrict__ VT,
                                                   unsigned short* __restrict__ AO) {
    int b = blockIdx.z, h = blockIdx.y;
    int qbase = blockIdx.x * 64;
    int tid = threadIdx.x;
    int wv = tid >> 6, lane = tid & 63;
    int fr = lane & 15, fg = lane >> 4;

    __shared__ alignas(16) unsigned short Kt[64][136];     // [key][d]
    __shared__ alignas(16) unsigned short VTt[128][72];    // [d][key]
    __shared__ alignas(16) unsigned short Pt[4][16][72];   // [wave][q][key] (wave-private)

    // Q fragment registers: serve as MFMA B-operand (Q^T[d][q=fr])
    const size_t qrow0 = ((size_t)b * Tn + qbase + wv * 16 + fr) * Dn + h * DH;
    s16x8 bq[4];
    #pragma unroll
    for (int c = 0; c < 4; c++) bq[c] = *(const s16x8*)&Q[qrow0 + c * 32 + fg * 8];

    f32x4 acc[8] = {};
    float m_run = -1e30f, l_run = 0.f;

    int krow = tid >> 2, kcol = (tid & 3) * 8;     // K staging: 4 x uint4 / thread
    int vrow = tid >> 1, vcol = (tid & 1) * 32;    // VT staging: 4 x uint4 / thread
    const unsigned short* kgb = K + ((size_t)b * Tn + krow) * Dn + h * DH + kcol;
    const unsigned short* vgb = VT + (((size_t)b * Hn + h) * DH + vrow) * Tn + vcol;

    for (int kb = 0; kb < Tn; kb += 64) {
        __syncthreads();   // previous iteration's readers done
        const unsigned short* kg = kgb + (size_t)kb * Dn;
        #pragma unroll
        for (int p = 0; p < 4; p++)
            *(uint4*)&Kt[krow][kcol + p * 32] = *(const uint4*)&kg[p * 32];
        const unsigned short* vg = vgb + kb;
        #pragma unroll
        for (int p = 0; p < 4; p++)
            *(uint4*)&VTt[vrow][vcol + p * 8] = *(const uint4*)&vg[p * 8];
        __syncthreads();

        // S^T = K Q^T : lane q = fr, key = kt*16 + fg*4 + r
        f32x4 s[4] = {};
        #pragma unroll
        for (int c = 0; c < 4; c++) {
            #pragma unroll
            for (int kt = 0; kt < 4; kt++) {
                s16x8 ak = *(const s16x8*)&Kt[kt * 16 + fr][c * 32 + fg * 8];
                s[kt] = mfma16(ak, bq[c], s[kt]);
            }
        }

        // in-register online softmax (exp2 domain; scale folded into Q)
        float mx = s[0][0];
        #pragma unroll
        for (int kt = 0; kt < 4; kt++)
            #pragma unroll
            for (int r = 0; r < 4; r++) mx = fmaxf(mx, s[kt][r]);
        mx = fmaxf(mx, __shfl_xor(mx, 16));
        mx = fmaxf(mx, __shfl_xor(mx, 32));

        if (!__all(mx - m_run <= 8.0f)) {          // T13 defer-max (log2 domain)
            float mnew = fmaxf(m_run, mx);
            float f = ex2(m_run - mnew);
            l_run *= f;
            float fw[4];
            #pragma unroll
            for (int r = 0; r < 4; r++) fw[r] = __shfl(f, fg * 4 + r);
            #pragma unroll
            for (int n = 0; n < 8; n++)
                #pragma unroll
                for (int r = 0; r < 4; r++) acc[n][r] *= fw[r];
            m_run = mnew;
        }

        float p[16];
        float sum = 0.f;
        #pragma unroll
        for (int kt = 0; kt < 4; kt++)
            #pragma unroll
            for (int r = 0; r < 4; r++) {
                float e = ex2(s[kt][r] - m_run);
                p[kt * 4 + r] = e;
                sum += e;
            }
        sum += __shfl_xor(sum, 16);
        sum += __shfl_xor(sum, 32);
        l_run += sum;

        // pack P -> Pt[q=fr][key], wave-private: no barrier needed
        #pragma unroll
        for (int kt = 0; kt < 4; kt++) {
            uint2 w;
            w.x = cvtpk(p[kt * 4 + 0], p[kt * 4 + 1]);
            w.y = cvtpk(p[kt * 4 + 2], p[kt * 4 + 3]);
            *(uint2*)&Pt[wv][fr][kt * 16 + fg * 4] = w;
        }

        // O += P V : A-frag from Pt (row q=fr, k=fg*8+j), B-frag contiguous from VTt
        #pragma unroll
        for (int ks = 0; ks < 2; ks++) {
            s16x8 pa = *(const s16x8*)&Pt[wv][fr][ks * 32 + fg * 8];
            #pragma unroll
            for (int n = 0; n < 8; n++) {
                s16x8 bv = *(const s16x8*)&VTt[n * 16 + fr][ks * 32 + fg * 8];
                acc[n] = mfma16(pa, bv, acc[n]);
            }
        }
    }

    // epilogue: acc row = q_local = fg*4+r, l lives on lane q_local -> fetch
    float rl[4];
    #pragma unroll
    for (int r = 0; r < 4; r++) rl[r] = 1.0f / __shfl(l_run, fg * 4 + r);
    size_t orow0 = ((size_t)b * Tn + qbase + wv * 16) * Dn + h * DH;
    for (int n = 0; n < 8; n++)
        for (int r = 0; r < 4; r++) {
            float v = acc[n][r] * rl[r];
            AO[orow0 + (size_t)(fg * 4 + r) * Dn + n * 16 + fr] = f2bf(v);
        }
}

// ---------------- O projection + pad + residual ----------------
__global__ __launch_bounds__(256) void oproj_gemm(const unsigned short* __restrict__ A,
                                                  const unsigned short* __restrict__ W,
                                                  const float* __restrict__ bias,
                                                  const float* __restrict__ x,
                                                  float* __restrict__ out) {
    int rowbase = blockIdx.x * 64;
    int colbase = blockIdx.y * 64;
    int e = (rowbase & (Tn - 1)) >> 9;
    int m = Dn >> e;
    int tid = threadIdx.x;

    if (colbase >= m) {   // pad region: pure residual copy
        for (int i = 0; i < 16; i++) {
            int idx = i * 256 + tid;
            int r = idx >> 6, c = idx & 63;
            size_t g = (size_t)(rowbase + r) * Dn + colbase + c;
            out[g] = x[g];
        }
        return;
    }

    __shared__ alignas(16) unsigned short At[64][32];
    __shared__ alignas(16) unsigned short Bt[64][32];
    int lr = tid >> 2, lc = (tid & 3) * 8;
    int lane = tid & 63, wv = tid >> 6;
    int wr = (wv >> 1) * 32, wc = (wv & 1) * 32;
    int fr = lane & 15, fg = lane >> 4;
    f32x4 acc[2][2] = {};

    for (int k = 0; k < m; k += 32) {
        __syncthreads();
        *(uint4*)&At[lr][lc] = *(const uint4*)&A[(size_t)(rowbase + lr) * Dn + k + lc];
        *(uint4*)&Bt[lr][lc] = *(const uint4*)&W[(size_t)(colbase + lr) * Dn + k + lc];
        __syncthreads();
        s16x8 a0 = *(const s16x8*)&At[wr + fr][fg * 8];
        s16x8 a1 = *(const s16x8*)&At[wr + 16 + fr][fg * 8];
        s16x8 b0 = *(const s16x8*)&Bt[wc + fr][fg * 8];
        s16x8 b1 = *(const s16x8*)&Bt[wc + 16 + fr][fg * 8];
        acc[0][0] = mfma16(a0, b0, acc[0][0]);
        acc[0][1] = mfma16(a0, b1, acc[0][1]);
        acc[1][0] = mfma16(a1, b0, acc[1][0]);
        acc[1][1] = mfma16(a1, b1, acc[1][1]);
    }
    for (int i = 0; i < 2; i++)
        for (int j = 0; j < 2; j++) {
            int col = colbase + wc + j * 16 + fr;
            float bv = bias[col];
            for (int r = 0; r < 4; r++) {
                int row = rowbase + wr + i * 16 + fg * 4 + r;
                size_t g = (size_t)row * Dn + col;
                out[g] = acc[i][j][r] + bv + x[g];
            }
        }
}

extern "C" void kernel_launch(void* const* d_in, const int* in_sizes, int n_in,
                              void* d_out, int out_size, void* d_ws, size_t ws_size,
                              hipStream_t stream) {
    const float* x   = (const float*)d_in[0];
    const float* nw  = (const float*)d_in[2];
    const float* nb  = (const float*)d_in[3];
    const float* qw  = (const float*)d_in[4];
    const float* qb_ = (const float*)d_in[5];
    const float* kw  = (const float*)d_in[6];
    const float* kb_ = (const float*)d_in[7];
    const float* vw  = (const float*)d_in[8];
    const float* vb_ = (const float*)d_in[9];
    const float* ow  = (const float*)d_in[10];
    const float* ob_ = (const float*)d_in[11];
    float* out = (float*)d_out;

    unsigned short* ws = (unsigned short*)d_ws;
    const size_t NTOK = (size_t)Bn * Tn;        // 8192
    unsigned short* xn = ws;                    // layernorm output, bf16
    unsigned short* qd = xn + NTOK * Dn;
    unsigned short* kd = qd + NTOK * Dn;
    unsigned short* vt = kd + NTOK * Dn;        // V transposed [B][H][DH][T]
    unsigned short* ao = vt + NTOK * Dn;        // attention output, bf16
    unsigned short* wb = ao + NTOK * Dn;        // [wq|wk|wv|wo] bf16

    hipLaunchKernelGGL(cvt_w_kernel, dim3(4096), dim3(256), 0, stream, qw, kw, vw, ow, wb);
    hipLaunchKernelGGL(ln_kernel, dim3(NTOK), dim3(256), 0, stream, x, nw, nb, xn);
    hipLaunchKernelGGL(qkv_gemm, dim3(128, 16, 3), dim3(256), 0, stream,
                       xn, wb, qb_, kb_, vb_, qd, kd, vt);
    hipLaunchKernelGGL(attn_kernel, dim3(Tn / 64, Hn, Bn), dim3(256), 0, stream, qd, kd, vt, ao);
    hipLaunchKernelGGL(oproj_gemm, dim3(128, 16), dim3(256), 0, stream,
                       ao, wb + (size_t)3 * Dn * Dn, ob_, x, out);
}

// Round 4
// 261.870 us; speedup vs baseline: 2.0789x; 1.1037x over previous
//
#include <hip/hip_runtime.h>
#include <hip/hip_bf16.h>

#define DEV static __device__ __forceinline__

typedef __attribute__((ext_vector_type(4))) float f32x4;
typedef __attribute__((ext_vector_type(8))) short s16x8;

constexpr int Bn = 4, Tn = 2048, Dn = 1024, Hn = 8, DH = 128;
constexpr float EPSF = 1e-5f;
// attn scale (1/32) * log2(e): softmax done in exp2 domain
constexpr float QSCALE = 0.0450842200277801f;

DEV unsigned short f2bf(float f) {
    unsigned int u = __float_as_uint(f);
    u += 0x7FFF + ((u >> 16) & 1);   // round-to-nearest-even
    return (unsigned short)(u >> 16);
}

DEV f32x4 mfma16(s16x8 a, s16x8 b, f32x4 c) {
    return __builtin_amdgcn_mfma_f32_16x16x32_bf16(a, b, c, 0, 0, 0);
}

DEV float ex2(float x) {            // v_exp_f32 IS exp2
    float r;
    asm("v_exp_f32 %0, %1" : "=v"(r) : "v"(x));
    return r;
}

DEV unsigned int cvtpk(float lo, float hi) {   // bf16(lo) | bf16(hi)<<16, RNE
    unsigned int r;
    asm("v_cvt_pk_bf16_f32 %0, %1, %2" : "=v"(r) : "v"(lo), "v"(hi));
    return r;
}

typedef __attribute__((address_space(1))) const unsigned int GU32;
typedef __attribute__((address_space(3))) unsigned int LU32;
DEV void gload16(const void* g, void* l) {     // async global->LDS, 16B/lane
    __builtin_amdgcn_global_load_lds((GU32*)g, (LU32*)l, 16, 0, 0);
}

// ---------------- weight f32 -> bf16 conversion ----------------
__global__ void cvt_w_kernel(const float* __restrict__ qw, const float* __restrict__ kw,
                             const float* __restrict__ vw, const float* __restrict__ ow,
                             unsigned short* __restrict__ dst) {
    int idx = blockIdx.x * blockDim.x + threadIdx.x;
    const int total = 4 * Dn * Dn;
    for (; idx < total; idx += gridDim.x * blockDim.x) {
        int sel = idx >> 20;              // Dn*Dn == 2^20
        int off = idx & (Dn * Dn - 1);
        const float* src = sel == 0 ? qw : sel == 1 ? kw : sel == 2 ? vw : ow;
        dst[idx] = f2bf(src[off]);
    }
}

// ---------------- layernorm (full D), f32 in -> bf16 out ----------------
__global__ __launch_bounds__(256) void ln_kernel(const float* __restrict__ x,
                                                 const float* __restrict__ w,
                                                 const float* __restrict__ b,
                                                 unsigned short* __restrict__ xn) {
    int tok = blockIdx.x;          // 0..8191
    int tid = threadIdx.x;         // 0..255, 4 floats each
    const float* xp = x + (size_t)tok * Dn;
    float4 v = ((const float4*)xp)[tid];
    float s = v.x + v.y + v.z + v.w;
    float q = v.x * v.x + v.y * v.y + v.z * v.z + v.w * v.w;
    for (int off = 32; off; off >>= 1) {
        s += __shfl_xor(s, off);
        q += __shfl_xor(q, off);
    }
    __shared__ float red[8];
    __shared__ float stats[2];
    int wid = tid >> 6, lane = tid & 63;
    if (lane == 0) { red[wid] = s; red[4 + wid] = q; }
    __syncthreads();
    if (tid == 0) {
        float ts = red[0] + red[1] + red[2] + red[3];
        float tq = red[4] + red[5] + red[6] + red[7];
        float mu = ts / Dn;
        float var = tq / Dn - mu * mu;
        stats[0] = mu;
        stats[1] = rsqrtf(var + EPSF);
    }
    __syncthreads();
    float mu = stats[0], rs = stats[1];
    int c = tid * 4;
    ushort4 o;
    o.x = f2bf((v.x - mu) * rs * w[c + 0] + b[c + 0]);
    o.y = f2bf((v.y - mu) * rs * w[c + 1] + b[c + 1]);
    o.z = f2bf((v.z - mu) * rs * w[c + 2] + b[c + 2]);
    o.w = f2bf((v.w - mu) * rs * w[c + 3] + b[c + 3]);
    ((ushort4*)(xn + (size_t)tok * Dn))[tid] = o;
}

// ---------------- QKV projection, m97-structure ----------------
// 128x128 tile, BK=32, 4 waves (64x64 quadrant each, 4x4 16x16 frags),
// global_load_lds width-16 staging into LINEAR [128][32] LDS tiles.
// V is written TRANSPOSED to vt[b][h][d][t].
__global__ __launch_bounds__(256) void qkv_gemm(const unsigned short* __restrict__ xn,
                                                const unsigned short* __restrict__ wmat,
                                                const float* __restrict__ qb_,
                                                const float* __restrict__ kb_,
                                                const float* __restrict__ vb_,
                                                unsigned short* __restrict__ outq,
                                                unsigned short* __restrict__ outk,
                                                unsigned short* __restrict__ vt) {
    int rowbase = blockIdx.x * 128;
    int colbase = blockIdx.y * 128;
    int matid = blockIdx.z;
    const unsigned short* W = wmat + (size_t)matid * Dn * Dn;
    const float* bias = matid == 0 ? qb_ : matid == 1 ? kb_ : vb_;
    float oscale = matid == 0 ? QSCALE : 1.0f;     // fold attn scale * log2e into Q
    int e = (rowbase & (Tn - 1)) >> 9;             // chunk within T (128 | 512)
    int m = Dn >> e;

    __shared__ alignas(16) unsigned short At[128 * 32];
    __shared__ alignas(16) unsigned short Bt[128 * 32];

    int tid = threadIdx.x;
    int lane = tid & 63, wv = tid >> 6;
    int wr = (wv >> 1) * 64, wc = (wv & 1) * 64;
    int fr = lane & 15, fg = lane >> 4;
    // staging: thread t, slice i: flat elem (i*256+t)*8 -> row=(i*256+t)>>2, col=(t&3)*8
    int srow = tid >> 2, scol = (tid & 3) * 8;
    const unsigned short* ga0 = xn + (size_t)(rowbase + srow) * Dn + scol;
    const unsigned short* ga1 = xn + (size_t)(rowbase + 64 + srow) * Dn + scol;
    const unsigned short* gb0 = W + (size_t)(colbase + srow) * Dn + scol;
    const unsigned short* gb1 = W + (size_t)(colbase + 64 + srow) * Dn + scol;
    unsigned short* la0 = At + tid * 8;
    unsigned short* la1 = At + 2048 + tid * 8;
    unsigned short* lb0 = Bt + tid * 8;
    unsigned short* lb1 = Bt + 2048 + tid * 8;

    f32x4 acc[4][4] = {};

    for (int k = 0; k < m; k += 32) {
        __syncthreads();
        gload16(ga0 + k, la0);
        gload16(ga1 + k, la1);
        gload16(gb0 + k, lb0);
        gload16(gb1 + k, lb1);
        __syncthreads();   // compiler drains vmcnt before s_barrier
        s16x8 a[4], b[4];
        #pragma unroll
        for (int i = 0; i < 4; i++) a[i] = *(const s16x8*)&At[(wr + i * 16 + fr) * 32 + fg * 8];
        #pragma unroll
        for (int j = 0; j < 4; j++) b[j] = *(const s16x8*)&Bt[(wc + j * 16 + fr) * 32 + fg * 8];
        #pragma unroll
        for (int i = 0; i < 4; i++)
            #pragma unroll
            for (int j = 0; j < 4; j++) acc[i][j] = mfma16(a[i], b[j], acc[i][j]);
    }

    if (matid == 2) {
        // V: write transposed vt[((b*H + h)*DH + dh)*Tn + t]
        #pragma unroll
        for (int i = 0; i < 4; i++)
            #pragma unroll
            for (int j = 0; j < 4; j++) {
                int col = colbase + wc + j * 16 + fr;
                float bv = bias[col];
                int row0 = rowbase + wr + i * 16 + fg * 4;   // 4 consecutive t
                int bb = row0 >> 11, tl = row0 & (Tn - 1);
                size_t base = (((size_t)bb * Hn + (col >> 7)) * DH + (col & (DH - 1))) * Tn + tl;
                ushort4 o;
                o.x = f2bf(acc[i][j][0] + bv);
                o.y = f2bf(acc[i][j][1] + bv);
                o.z = f2bf(acc[i][j][2] + bv);
                o.w = f2bf(acc[i][j][3] + bv);
                *(ushort4*)&vt[base] = o;
            }
    } else {
        unsigned short* out = matid == 0 ? outq : outk;
        #pragma unroll
        for (int i = 0; i < 4; i++)
            #pragma unroll
            for (int j = 0; j < 4; j++) {
                int col = colbase + wc + j * 16 + fr;
                float bv = bias[col];
                #pragma unroll
                for (int r = 0; r < 4; r++) {
                    int row = rowbase + wr + i * 16 + fg * 4 + r;
                    out[(size_t)row * Dn + col] = f2bf((acc[i][j][r] + bv) * oscale);
                }
            }
    }
}

// ---------------- flash attention: 32 q/wave, swapped-QK in-register softmax ----
// grid (T/128, H, B) = 512 blocks; 4 waves x 32 queries, KVBLK=64.
// K/V fragments read once from LDS and shared across the two q-halves:
// 52 DS ops per 64 MFMA per wave-iter (vs 62/32 before).
__global__ __launch_bounds__(256, 2) void attn_kernel(const unsigned short* __restrict__ Q,
                                                      const unsigned short* __restrict__ K,
                                                      const unsigned short* __restrict__ VT,
                                                      unsigned short* __restrict__ AO) {
    int b = blockIdx.z, h = blockIdx.y;
    int qbase = blockIdx.x * 128;
    int tid = threadIdx.x;
    int wv = tid >> 6, lane = tid & 63;
    int fr = lane & 15, fg = lane >> 4;

    __shared__ alignas(16) unsigned short Kt[64][136];     // [key][d]
    __shared__ alignas(16) unsigned short VTt[128][72];    // [d][key]
    __shared__ alignas(16) unsigned short Pt[4][32][72];   // [wave][q][key] (wave-private)

    // Q fragments for both halves: B-operand (Q^T[d][q=fr])
    s16x8 bq[2][4];
    #pragma unroll
    for (int hh = 0; hh < 2; hh++) {
        const size_t qr = ((size_t)b * Tn + qbase + wv * 32 + hh * 16 + fr) * Dn + h * DH;
        #pragma unroll
        for (int c = 0; c < 4; c++) bq[hh][c] = *(const s16x8*)&Q[qr + c * 32 + fg * 8];
    }

    f32x4 acc[2][8] = {};
    float m_run[2] = {-1e30f, -1e30f};
    float l_run[2] = {0.f, 0.f};

    int krow = tid >> 2, kcol = (tid & 3) * 8;     // K staging: 4 x uint4 / thread
    int vrow = tid >> 1, vcol = (tid & 1) * 32;    // VT staging: 4 x uint4 / thread
    const unsigned short* kgb = K + ((size_t)b * Tn + krow) * Dn + h * DH + kcol;
    const unsigned short* vgb = VT + (((size_t)b * Hn + h) * DH + vrow) * Tn + vcol;

    for (int kb = 0; kb < Tn; kb += 64) {
        __syncthreads();   // previous iteration's readers done
        const unsigned short* kg = kgb + (size_t)kb * Dn;
        #pragma unroll
        for (int p = 0; p < 4; p++)
            *(uint4*)&Kt[krow][kcol + p * 32] = *(const uint4*)&kg[p * 32];
        const unsigned short* vg = vgb + kb;
        #pragma unroll
        for (int p = 0; p < 4; p++)
            *(uint4*)&VTt[vrow][vcol + p * 8] = *(const uint4*)&vg[p * 8];
        __syncthreads();

        // S^T = K Q^T, both halves share each K fragment read
        f32x4 s[2][4] = {};
        #pragma unroll
        for (int c = 0; c < 4; c++) {
            #pragma unroll
            for (int kt = 0; kt < 4; kt++) {
                s16x8 ak = *(const s16x8*)&Kt[kt * 16 + fr][c * 32 + fg * 8];
                s[0][kt] = mfma16(ak, bq[0][c], s[0][kt]);
                s[1][kt] = mfma16(ak, bq[1][c], s[1][kt]);
            }
        }

        // in-register online softmax per half (exp2 domain)
        float mx[2];
        #pragma unroll
        for (int hh = 0; hh < 2; hh++) {
            float v = s[hh][0][0];
            #pragma unroll
            for (int kt = 0; kt < 4; kt++)
                #pragma unroll
                for (int r = 0; r < 4; r++) v = fmaxf(v, s[hh][kt][r]);
            v = fmaxf(v, __shfl_xor(v, 16));
            v = fmaxf(v, __shfl_xor(v, 32));
            mx[hh] = v;
        }

        bool need = !__all(mx[0] - m_run[0] <= 8.0f && mx[1] - m_run[1] <= 8.0f);
        if (need) {        // T13 defer-max
            #pragma unroll
            for (int hh = 0; hh < 2; hh++) {
                float mnew = fmaxf(m_run[hh], mx[hh]);
                float f = ex2(m_run[hh] - mnew);
                l_run[hh] *= f;
                float fw[4];
                #pragma unroll
                for (int r = 0; r < 4; r++) fw[r] = __shfl(f, fg * 4 + r);
                #pragma unroll
                for (int n = 0; n < 8; n++)
                    #pragma unroll
                    for (int r = 0; r < 4; r++) acc[hh][n][r] *= fw[r];
                m_run[hh] = mnew;
            }
        }

        #pragma unroll
        for (int hh = 0; hh < 2; hh++) {
            float p[16];
            float sum = 0.f;
            #pragma unroll
            for (int kt = 0; kt < 4; kt++)
                #pragma unroll
                for (int r = 0; r < 4; r++) {
                    float ev = ex2(s[hh][kt][r] - m_run[hh]);
                    p[kt * 4 + r] = ev;
                    sum += ev;
                }
            sum += __shfl_xor(sum, 16);
            sum += __shfl_xor(sum, 32);
            l_run[hh] += sum;
            #pragma unroll
            for (int kt = 0; kt < 4; kt++) {
                uint2 w;
                w.x = cvtpk(p[kt * 4 + 0], p[kt * 4 + 1]);
                w.y = cvtpk(p[kt * 4 + 2], p[kt * 4 + 3]);
                *(uint2*)&Pt[wv][hh * 16 + fr][kt * 16 + fg * 4] = w;
            }
        }

        // O += P V : V fragments shared across halves
        #pragma unroll
        for (int ks = 0; ks < 2; ks++) {
            s16x8 pa0 = *(const s16x8*)&Pt[wv][fr][ks * 32 + fg * 8];
            s16x8 pa1 = *(const s16x8*)&Pt[wv][16 + fr][ks * 32 + fg * 8];
            #pragma unroll
            for (int n = 0; n < 8; n++) {
                s16x8 bv = *(const s16x8*)&VTt[n * 16 + fr][ks * 32 + fg * 8];
                acc[0][n] = mfma16(pa0, bv, acc[0][n]);
                acc[1][n] = mfma16(pa1, bv, acc[1][n]);
            }
        }
    }

    // epilogue: acc row = q_local = fg*4+r; l lives on lane q_local -> fetch
    #pragma unroll
    for (int hh = 0; hh < 2; hh++) {
        float rl[4];
        #pragma unroll
        for (int r = 0; r < 4; r++) rl[r] = 1.0f / __shfl(l_run[hh], fg * 4 + r);
        size_t orow0 = ((size_t)b * Tn + qbase + wv * 32 + hh * 16) * Dn + h * DH;
        for (int n = 0; n < 8; n++)
            for (int r = 0; r < 4; r++) {
                float v = acc[hh][n][r] * rl[r];
                AO[orow0 + (size_t)(fg * 4 + r) * Dn + n * 16 + fr] = f2bf(v);
            }
    }
}

// ---------------- O projection + pad + residual ----------------
__global__ __launch_bounds__(256) void oproj_gemm(const unsigned short* __restrict__ A,
                                                  const unsigned short* __restrict__ W,
                                                  const float* __restrict__ bias,
                                                  const float* __restrict__ x,
                                                  float* __restrict__ out) {
    int rowbase = blockIdx.x * 64;
    int colbase = blockIdx.y * 64;
    int e = (rowbase & (Tn - 1)) >> 9;
    int m = Dn >> e;
    int tid = threadIdx.x;

    if (colbase >= m) {   // pad region: pure residual copy
        for (int i = 0; i < 16; i++) {
            int idx = i * 256 + tid;
            int r = idx >> 6, c = idx & 63;
            size_t g = (size_t)(rowbase + r) * Dn + colbase + c;
            out[g] = x[g];
        }
        return;
    }

    __shared__ alignas(16) unsigned short At[64][32];
    __shared__ alignas(16) unsigned short Bt[64][32];
    int lr = tid >> 2, lc = (tid & 3) * 8;
    int lane = tid & 63, wv = tid >> 6;
    int wr = (wv >> 1) * 32, wc = (wv & 1) * 32;
    int fr = lane & 15, fg = lane >> 4;
    f32x4 acc[2][2] = {};

    for (int k = 0; k < m; k += 32) {
        __syncthreads();
        *(uint4*)&At[lr][lc] = *(const uint4*)&A[(size_t)(rowbase + lr) * Dn + k + lc];
        *(uint4*)&Bt[lr][lc] = *(const uint4*)&W[(size_t)(colbase + lr) * Dn + k + lc];
        __syncthreads();
        s16x8 a0 = *(const s16x8*)&At[wr + fr][fg * 8];
        s16x8 a1 = *(const s16x8*)&At[wr + 16 + fr][fg * 8];
        s16x8 b0 = *(const s16x8*)&Bt[wc + fr][fg * 8];
        s16x8 b1 = *(const s16x8*)&Bt[wc + 16 + fr][fg * 8];
        acc[0][0] = mfma16(a0, b0, acc[0][0]);
        acc[0][1] = mfma16(a0, b1, acc[0][1]);
        acc[1][0] = mfma16(a1, b0, acc[1][0]);
        acc[1][1] = mfma16(a1, b1, acc[1][1]);
    }
    for (int i = 0; i < 2; i++)
        for (int j = 0; j < 2; j++) {
            int col = colbase + wc + j * 16 + fr;
            float bv = bias[col];
            for (int r = 0; r < 4; r++) {
                int row = rowbase + wr + i * 16 + fg * 4 + r;
                size_t g = (size_t)row * Dn + col;
                out[g] = acc[i][j][r] + bv + x[g];
            }
        }
}

extern "C" void kernel_launch(void* const* d_in, const int* in_sizes, int n_in,
                              void* d_out, int out_size, void* d_ws, size_t ws_size,
                              hipStream_t stream) {
    const float* x   = (const float*)d_in[0];
    const float* nw  = (const float*)d_in[2];
    const float* nb  = (const float*)d_in[3];
    const float* qw  = (const float*)d_in[4];
    const float* qb_ = (const float*)d_in[5];
    const float* kw  = (const float*)d_in[6];
    const float* kb_ = (const float*)d_in[7];
    const float* vw  = (const float*)d_in[8];
    const float* vb_ = (const float*)d_in[9];
    const float* ow  = (const float*)d_in[10];
    const float* ob_ = (const float*)d_in[11];
    float* out = (float*)d_out;

    unsigned short* ws = (unsigned short*)d_ws;
    const size_t NTOK = (size_t)Bn * Tn;        // 8192
    unsigned short* xn = ws;                    // layernorm output, bf16
    unsigned short* qd = xn + NTOK * Dn;
    unsigned short* kd = qd + NTOK * Dn;
    unsigned short* vt = kd + NTOK * Dn;        // V transposed [B][H][DH][T]
    unsigned short* ao = vt + NTOK * Dn;        // attention output, bf16
    unsigned short* wb = ao + NTOK * Dn;        // [wq|wk|wv|wo] bf16

    hipLaunchKernelGGL(cvt_w_kernel, dim3(4096), dim3(256), 0, stream, qw, kw, vw, ow, wb);
    hipLaunchKernelGGL(ln_kernel, dim3(NTOK), dim3(256), 0, stream, x, nw, nb, xn);
    hipLaunchKernelGGL(qkv_gemm, dim3(64, 8, 3), dim3(256), 0, stream,
                       xn, wb, qb_, kb_, vb_, qd, kd, vt);
    hipLaunchKernelGGL(attn_kernel, dim3(Tn / 128, Hn, Bn), dim3(256), 0, stream, qd, kd, vt, ao);
    hipLaunchKernelGGL(oproj_gemm, dim3(128, 16), dim3(256), 0, stream,
                       ao, wb + (size_t)3 * Dn * Dn, ob_, x, out);
}

// Round 5
// 210.402 us; speedup vs baseline: 2.5874x; 1.2446x over previous
//
#include <hip/hip_runtime.h>
#include <hip/hip_bf16.h>

#define DEV static __device__ __forceinline__

typedef __attribute__((ext_vector_type(4))) float f32x4;
typedef __attribute__((ext_vector_type(8))) short s16x8;

constexpr int Bn = 4, Tn = 2048, Dn = 1024, Hn = 8, DH = 128;
constexpr float EPSF = 1e-5f;
// attn scale (1/32) * log2(e): softmax done in exp2 domain
constexpr float QSCALE = 0.0450842200277801f;

DEV unsigned short f2bf(float f) {
    unsigned int u = __float_as_uint(f);
    u += 0x7FFF + ((u >> 16) & 1);   // round-to-nearest-even
    return (unsigned short)(u >> 16);
}

DEV f32x4 mfma16(s16x8 a, s16x8 b, f32x4 c) {
    return __builtin_amdgcn_mfma_f32_16x16x32_bf16(a, b, c, 0, 0, 0);
}

DEV float ex2(float x) {            // v_exp_f32 IS exp2
    float r;
    asm("v_exp_f32 %0, %1" : "=v"(r) : "v"(x));
    return r;
}

DEV unsigned int cvtpk(float lo, float hi) {   // bf16(lo) | bf16(hi)<<16, RNE
    unsigned int r;
    asm("v_cvt_pk_bf16_f32 %0, %1, %2" : "=v"(r) : "v"(lo), "v"(hi));
    return r;
}

typedef __attribute__((address_space(1))) const unsigned int GU32;
typedef __attribute__((address_space(3))) unsigned int LU32;
DEV void gload16(const void* g, void* l) {     // async global->LDS, 16B/lane
    __builtin_amdgcn_global_load_lds((GU32*)g, (LU32*)l, 16, 0, 0);
}

// ---------------- weight f32 -> bf16 conversion ----------------
__global__ void cvt_w_kernel(const float* __restrict__ qw, const float* __restrict__ kw,
                             const float* __restrict__ vw, const float* __restrict__ ow,
                             unsigned short* __restrict__ dst) {
    int idx = blockIdx.x * blockDim.x + threadIdx.x;
    const int total = 4 * Dn * Dn;
    for (; idx < total; idx += gridDim.x * blockDim.x) {
        int sel = idx >> 20;              // Dn*Dn == 2^20
        int off = idx & (Dn * Dn - 1);
        const float* src = sel == 0 ? qw : sel == 1 ? kw : sel == 2 ? vw : ow;
        dst[idx] = f2bf(src[off]);
    }
}

// ---------------- layernorm (full D), f32 in -> bf16 out ----------------
__global__ __launch_bounds__(256) void ln_kernel(const float* __restrict__ x,
                                                 const float* __restrict__ w,
                                                 const float* __restrict__ b,
                                                 unsigned short* __restrict__ xn) {
    int tok = blockIdx.x;          // 0..8191
    int tid = threadIdx.x;         // 0..255, 4 floats each
    const float* xp = x + (size_t)tok * Dn;
    float4 v = ((const float4*)xp)[tid];
    float s = v.x + v.y + v.z + v.w;
    float q = v.x * v.x + v.y * v.y + v.z * v.z + v.w * v.w;
    for (int off = 32; off; off >>= 1) {
        s += __shfl_xor(s, off);
        q += __shfl_xor(q, off);
    }
    __shared__ float red[8];
    __shared__ float stats[2];
    int wid = tid >> 6, lane = tid & 63;
    if (lane == 0) { red[wid] = s; red[4 + wid] = q; }
    __syncthreads();
    if (tid == 0) {
        float ts = red[0] + red[1] + red[2] + red[3];
        float tq = red[4] + red[5] + red[6] + red[7];
        float mu = ts / Dn;
        float var = tq / Dn - mu * mu;
        stats[0] = mu;
        stats[1] = rsqrtf(var + EPSF);
    }
    __syncthreads();
    float mu = stats[0], rs = stats[1];
    int c = tid * 4;
    ushort4 o;
    o.x = f2bf((v.x - mu) * rs * w[c + 0] + b[c + 0]);
    o.y = f2bf((v.y - mu) * rs * w[c + 1] + b[c + 1]);
    o.z = f2bf((v.z - mu) * rs * w[c + 2] + b[c + 2]);
    o.w = f2bf((v.w - mu) * rs * w[c + 3] + b[c + 3]);
    ((ushort4*)(xn + (size_t)tok * Dn))[tid] = o;
}

// ---------------- QKV projection, m97-structure ----------------
__global__ __launch_bounds__(256) void qkv_gemm(const unsigned short* __restrict__ xn,
                                                const unsigned short* __restrict__ wmat,
                                                const float* __restrict__ qb_,
                                                const float* __restrict__ kb_,
                                                const float* __restrict__ vb_,
                                                unsigned short* __restrict__ outq,
                                                unsigned short* __restrict__ outk,
                                                unsigned short* __restrict__ vt) {
    int rowbase = blockIdx.x * 128;
    int colbase = blockIdx.y * 128;
    int matid = blockIdx.z;
    const unsigned short* W = wmat + (size_t)matid * Dn * Dn;
    const float* bias = matid == 0 ? qb_ : matid == 1 ? kb_ : vb_;
    float oscale = matid == 0 ? QSCALE : 1.0f;     // fold attn scale * log2e into Q
    int e = (rowbase & (Tn - 1)) >> 9;             // chunk within T
    int m = Dn >> e;

    __shared__ alignas(16) unsigned short At[128 * 32];
    __shared__ alignas(16) unsigned short Bt[128 * 32];

    int tid = threadIdx.x;
    int lane = tid & 63, wv = tid >> 6;
    int wr = (wv >> 1) * 64, wc = (wv & 1) * 64;
    int fr = lane & 15, fg = lane >> 4;
    int srow = tid >> 2, scol = (tid & 3) * 8;
    const unsigned short* ga0 = xn + (size_t)(rowbase + srow) * Dn + scol;
    const unsigned short* ga1 = xn + (size_t)(rowbase + 64 + srow) * Dn + scol;
    const unsigned short* gb0 = W + (size_t)(colbase + srow) * Dn + scol;
    const unsigned short* gb1 = W + (size_t)(colbase + 64 + srow) * Dn + scol;
    unsigned short* la0 = At + tid * 8;
    unsigned short* la1 = At + 2048 + tid * 8;
    unsigned short* lb0 = Bt + tid * 8;
    unsigned short* lb1 = Bt + 2048 + tid * 8;

    f32x4 acc[4][4] = {};

    for (int k = 0; k < m; k += 32) {
        __syncthreads();
        gload16(ga0 + k, la0);
        gload16(ga1 + k, la1);
        gload16(gb0 + k, lb0);
        gload16(gb1 + k, lb1);
        __syncthreads();
        s16x8 a[4], b[4];
        #pragma unroll
        for (int i = 0; i < 4; i++) a[i] = *(const s16x8*)&At[(wr + i * 16 + fr) * 32 + fg * 8];
        #pragma unroll
        for (int j = 0; j < 4; j++) b[j] = *(const s16x8*)&Bt[(wc + j * 16 + fr) * 32 + fg * 8];
        #pragma unroll
        for (int i = 0; i < 4; i++)
            #pragma unroll
            for (int j = 0; j < 4; j++) acc[i][j] = mfma16(a[i], b[j], acc[i][j]);
    }

    if (matid == 2) {
        // V: write transposed vt[((b*H + h)*DH + dh)*Tn + t]
        #pragma unroll
        for (int i = 0; i < 4; i++)
            #pragma unroll
            for (int j = 0; j < 4; j++) {
                int col = colbase + wc + j * 16 + fr;
                float bv = bias[col];
                int row0 = rowbase + wr + i * 16 + fg * 4;
                int bb = row0 >> 11, tl = row0 & (Tn - 1);
                size_t base = (((size_t)bb * Hn + (col >> 7)) * DH + (col & (DH - 1))) * Tn + tl;
                ushort4 o;
                o.x = f2bf(acc[i][j][0] + bv);
                o.y = f2bf(acc[i][j][1] + bv);
                o.z = f2bf(acc[i][j][2] + bv);
                o.w = f2bf(acc[i][j][3] + bv);
                *(ushort4*)&vt[base] = o;
            }
    } else {
        unsigned short* out = matid == 0 ? outq : outk;
        #pragma unroll
        for (int i = 0; i < 4; i++)
            #pragma unroll
            for (int j = 0; j < 4; j++) {
                int col = colbase + wc + j * 16 + fr;
                float bv = bias[col];
                #pragma unroll
                for (int r = 0; r < 4; r++) {
                    int row = rowbase + wr + i * 16 + fg * 4 + r;
                    out[(size_t)row * Dn + col] = f2bf((acc[i][j][r] + bv) * oscale);
                }
            }
    }
}

// ---------------- flash attention: 8 waves x 32q, DMA-staged dbuf K/V ----------
// grid (T/256, H, B) = 256 blocks (1/CU), 512 threads.
// K/V staged via global_load_lds into LINEAR LDS with XOR-swizzled SOURCE
// addresses; reads apply the same XOR -> bank-floor access, zero ds_writes.
// 2-phase pipeline: STAGE(t+1) -> compute(t) -> one __syncthreads per iter.
__global__ __launch_bounds__(512, 1) void attn_kernel(const unsigned short* __restrict__ Q,
                                                      const unsigned short* __restrict__ K,
                                                      const unsigned short* __restrict__ VT,
                                                      unsigned short* __restrict__ AO) {
    int b = blockIdx.z, h = blockIdx.y;
    int qbase = blockIdx.x * 256;
    int tid = threadIdx.x;
    int wv = tid >> 6, lane = tid & 63;
    int fr = lane & 15, fg = lane >> 4;

    __shared__ alignas(16) unsigned short Kt[2][64 * 128];   // [key][d], swizzled chunks
    __shared__ alignas(16) unsigned short Vt[2][128 * 64];   // [d][key], swizzled chunks
    __shared__ alignas(16) unsigned short Pt[8][32][72];     // [wave][q][key] wave-private

    // Q fragments for both q-halves (B-operand: Q^T[d][q=fr])
    s16x8 bq[2][4];
    #pragma unroll
    for (int hh = 0; hh < 2; hh++) {
        const size_t qr = ((size_t)b * Tn + qbase + wv * 32 + hh * 16 + fr) * Dn + h * DH;
        #pragma unroll
        for (int c = 0; c < 4; c++) bq[hh][c] = *(const s16x8*)&Q[qr + c * 32 + fg * 8];
    }

    f32x4 acc[2][8] = {};
    float m_run[2] = {-1e30f, -1e30f};
    float l_run[2] = {0.f, 0.f};

    const unsigned short* Kbase = K + (size_t)b * Tn * Dn + h * DH;
    const unsigned short* Vbase = VT + ((size_t)b * Hn + h) * DH * Tn;

    // staging geometry (512 threads, 16B each, 2 instr per matrix)
    int krow_lo = tid >> 4, kchk = tid & 15;   // K: row=p*32+krow_lo, chunk'=kchk
    int vrow_lo = tid >> 3, vchk = tid & 7;    // V: row=p*64+vrow_lo, chunk'=vchk

    auto STAGE = [&](int t, int buf) {
        int kb = t * 64;
        #pragma unroll
        for (int p = 0; p < 2; p++) {
            int row = p * 32 + krow_lo;
            int chunk = kchk ^ (row & 7);
            gload16(Kbase + (size_t)(kb + row) * Dn + chunk * 8,
                    &Kt[buf][p * 4096 + tid * 8]);
        }
        #pragma unroll
        for (int p = 0; p < 2; p++) {
            int row = p * 64 + vrow_lo;
            int chunk = vchk ^ (row & 7);
            gload16(Vbase + (size_t)row * Tn + kb + chunk * 8,
                    &Vt[buf][p * 4096 + tid * 8]);
        }
    };

    STAGE(0, 0);
    __syncthreads();

    for (int t = 0; t < Tn / 64; t++) {
        int cur = t & 1;
        if (t < Tn / 64 - 1) STAGE(t + 1, cur ^ 1);

        const unsigned short* KtC = &Kt[cur][0];
        const unsigned short* VtC = &Vt[cur][0];

        // S^T = K Q^T : lane q = fr, key = kt*16 + fg*4 + r
        f32x4 s[2][4] = {};
        #pragma unroll
        for (int c = 0; c < 4; c++) {
            #pragma unroll
            for (int kt = 0; kt < 4; kt++) {
                s16x8 ak = *(const s16x8*)&KtC[(kt * 16 + fr) * 128 +
                                               (((c * 4 + fg) ^ (fr & 7)) * 8)];
                s[0][kt] = mfma16(ak, bq[0][c], s[0][kt]);
                s[1][kt] = mfma16(ak, bq[1][c], s[1][kt]);
            }
        }

        // in-register online softmax per half (exp2 domain)
        float mx[2];
        #pragma unroll
        for (int hh = 0; hh < 2; hh++) {
            float v = s[hh][0][0];
            #pragma unroll
            for (int kt = 0; kt < 4; kt++)
                #pragma unroll
                for (int r = 0; r < 4; r++) v = fmaxf(v, s[hh][kt][r]);
            v = fmaxf(v, __shfl_xor(v, 16));
            v = fmaxf(v, __shfl_xor(v, 32));
            mx[hh] = v;
        }

        if (!__all(mx[0] - m_run[0] <= 8.0f && mx[1] - m_run[1] <= 8.0f)) {  // T13
            #pragma unroll
            for (int hh = 0; hh < 2; hh++) {
                float mnew = fmaxf(m_run[hh], mx[hh]);
                float f = ex2(m_run[hh] - mnew);
                l_run[hh] *= f;
                float fw[4];
                #pragma unroll
                for (int r = 0; r < 4; r++) fw[r] = __shfl(f, fg * 4 + r);
                #pragma unroll
                for (int n = 0; n < 8; n++)
                    #pragma unroll
                    for (int r = 0; r < 4; r++) acc[hh][n][r] *= fw[r];
                m_run[hh] = mnew;
            }
        }

        #pragma unroll
        for (int hh = 0; hh < 2; hh++) {
            float p[16];
            float sum = 0.f;
            #pragma unroll
            for (int kt = 0; kt < 4; kt++)
                #pragma unroll
                for (int r = 0; r < 4; r++) {
                    float ev = ex2(s[hh][kt][r] - m_run[hh]);
                    p[kt * 4 + r] = ev;
                    sum += ev;
                }
            sum += __shfl_xor(sum, 16);
            sum += __shfl_xor(sum, 32);
            l_run[hh] += sum;
            #pragma unroll
            for (int kt = 0; kt < 4; kt++) {
                uint2 w;
                w.x = cvtpk(p[kt * 4 + 0], p[kt * 4 + 1]);
                w.y = cvtpk(p[kt * 4 + 2], p[kt * 4 + 3]);
                *(uint2*)&Pt[wv][hh * 16 + fr][kt * 16 + fg * 4] = w;
            }
        }

        // O += P V : V fragments shared across halves (swizzled read)
        #pragma unroll
        for (int ks = 0; ks < 2; ks++) {
            s16x8 pa0 = *(const s16x8*)&Pt[wv][fr][ks * 32 + fg * 8];
            s16x8 pa1 = *(const s16x8*)&Pt[wv][16 + fr][ks * 32 + fg * 8];
            #pragma unroll
            for (int n = 0; n < 8; n++) {
                s16x8 bv = *(const s16x8*)&VtC[(n * 16 + fr) * 64 +
                                               (((ks * 4 + fg) ^ (fr & 7)) * 8)];
                acc[0][n] = mfma16(pa0, bv, acc[0][n]);
                acc[1][n] = mfma16(pa1, bv, acc[1][n]);
            }
        }
        __syncthreads();   // drains vmcnt (STAGE t+1) + protects buffers
    }

    #pragma unroll
    for (int hh = 0; hh < 2; hh++) {
        float rl[4];
        #pragma unroll
        for (int r = 0; r < 4; r++) rl[r] = 1.0f / __shfl(l_run[hh], fg * 4 + r);
        size_t orow0 = ((size_t)b * Tn + qbase + wv * 32 + hh * 16) * Dn + h * DH;
        for (int n = 0; n < 8; n++)
            for (int r = 0; r < 4; r++) {
                float v = acc[hh][n][r] * rl[r];
                AO[orow0 + (size_t)(fg * 4 + r) * Dn + n * 16 + fr] = f2bf(v);
            }
    }
}

// ---------------- O projection + pad + residual, m97-structure ----------------
__global__ __launch_bounds__(256) void oproj_gemm(const unsigned short* __restrict__ A,
                                                  const unsigned short* __restrict__ W,
                                                  const float* __restrict__ bias,
                                                  const float* __restrict__ x,
                                                  float* __restrict__ out) {
    int rowbase = blockIdx.x * 128;
    int colbase = blockIdx.y * 128;
    int e = (rowbase & (Tn - 1)) >> 9;
    int m = Dn >> e;
    int tid = threadIdx.x;

    if (colbase >= m) {   // pad region: pure residual copy (128x128 f32)
        #pragma unroll
        for (int i = 0; i < 16; i++) {
            int idx = i * 256 + tid;
            int r = idx >> 5, c4 = (idx & 31) * 4;
            size_t g = (size_t)(rowbase + r) * Dn + colbase + c4;
            *(float4*)&out[g] = *(const float4*)&x[g];
        }
        return;
    }

    __shared__ alignas(16) unsigned short At[128 * 32];
    __shared__ alignas(16) unsigned short Bt[128 * 32];
    int lane = tid & 63, wv = tid >> 6;
    int wr = (wv >> 1) * 64, wc = (wv & 1) * 64;
    int fr = lane & 15, fg = lane >> 4;
    int srow = tid >> 2, scol = (tid & 3) * 8;
    const unsigned short* ga0 = A + (size_t)(rowbase + srow) * Dn + scol;
    const unsigned short* ga1 = A + (size_t)(rowbase + 64 + srow) * Dn + scol;
    const unsigned short* gb0 = W + (size_t)(colbase + srow) * Dn + scol;
    const unsigned short* gb1 = W + (size_t)(colbase + 64 + srow) * Dn + scol;
    unsigned short* la0 = At + tid * 8;
    unsigned short* la1 = At + 2048 + tid * 8;
    unsigned short* lb0 = Bt + tid * 8;
    unsigned short* lb1 = Bt + 2048 + tid * 8;

    f32x4 acc[4][4] = {};

    for (int k = 0; k < m; k += 32) {
        __syncthreads();
        gload16(ga0 + k, la0);
        gload16(ga1 + k, la1);
        gload16(gb0 + k, lb0);
        gload16(gb1 + k, lb1);
        __syncthreads();
        s16x8 a[4], b[4];
        #pragma unroll
        for (int i = 0; i < 4; i++) a[i] = *(const s16x8*)&At[(wr + i * 16 + fr) * 32 + fg * 8];
        #pragma unroll
        for (int j = 0; j < 4; j++) b[j] = *(const s16x8*)&Bt[(wc + j * 16 + fr) * 32 + fg * 8];
        #pragma unroll
        for (int i = 0; i < 4; i++)
            #pragma unroll
            for (int j = 0; j < 4; j++) acc[i][j] = mfma16(a[i], b[j], acc[i][j]);
    }

    #pragma unroll
    for (int i = 0; i < 4; i++)
        #pragma unroll
        for (int j = 0; j < 4; j++) {
            int col = colbase + wc + j * 16 + fr;
            float bv = bias[col];
            #pragma unroll
            for (int r = 0; r < 4; r++) {
                int row = rowbase + wr + i * 16 + fg * 4 + r;
                size_t g = (size_t)row * Dn + col;
                out[g] = acc[i][j][r] + bv + x[g];
            }
        }
}

extern "C" void kernel_launch(void* const* d_in, const int* in_sizes, int n_in,
                              void* d_out, int out_size, void* d_ws, size_t ws_size,
                              hipStream_t stream) {
    const float* x   = (const float*)d_in[0];
    const float* nw  = (const float*)d_in[2];
    const float* nb  = (const float*)d_in[3];
    const float* qw  = (const float*)d_in[4];
    const float* qb_ = (const float*)d_in[5];
    const float* kw  = (const float*)d_in[6];
    const float* kb_ = (const float*)d_in[7];
    const float* vw  = (const float*)d_in[8];
    const float* vb_ = (const float*)d_in[9];
    const float* ow  = (const float*)d_in[10];
    const float* ob_ = (const float*)d_in[11];
    float* out = (float*)d_out;

    unsigned short* ws = (unsigned short*)d_ws;
    const size_t NTOK = (size_t)Bn * Tn;        // 8192
    unsigned short* xn = ws;                    // layernorm output, bf16
    unsigned short* qd = xn + NTOK * Dn;
    unsigned short* kd = qd + NTOK * Dn;
    unsigned short* vt = kd + NTOK * Dn;        // V transposed [B][H][DH][T]
    unsigned short* ao = vt + NTOK * Dn;        // attention output, bf16
    unsigned short* wb = ao + NTOK * Dn;        // [wq|wk|wv|wo] bf16

    hipLaunchKernelGGL(cvt_w_kernel, dim3(4096), dim3(256), 0, stream, qw, kw, vw, ow, wb);
    hipLaunchKernelGGL(ln_kernel, dim3(NTOK), dim3(256), 0, stream, x, nw, nb, xn);
    hipLaunchKernelGGL(qkv_gemm, dim3(64, 8, 3), dim3(256), 0, stream,
                       xn, wb, qb_, kb_, vb_, qd, kd, vt);
    hipLaunchKernelGGL(attn_kernel, dim3(Tn / 256, Hn, Bn), dim3(512), 0, stream, qd, kd, vt, ao);
    hipLaunchKernelGGL(oproj_gemm, dim3(64, 8), dim3(256), 0, stream,
                       ao, wb + (size_t)3 * Dn * Dn, ob_, x, out);
}